// Round 16
// baseline (401.936 us; speedup 1.0000x reference)
//
#include <hip/hip_runtime.h>
#include <hip/hip_bf16.h>

#define D_H 128

typedef __attribute__((ext_vector_type(8)))  short bf16x8;
typedef __attribute__((ext_vector_type(16))) float f32x16;

typedef __attribute__((address_space(3))) uint lds_uint;
typedef __attribute__((address_space(1))) const uint glb_uint;

// async 16B/lane global->LDS copy: lds base wave-uniform, gsrc per-lane
__device__ __forceinline__ void lds_dma16(uint* lds_base, const uint4* gsrc) {
    __builtin_amdgcn_global_load_lds((glb_uint*)gsrc, (lds_uint*)lds_base, 16, 0, 0);
}

// truncation hi/lo bf16 split: hi = top16(x), lo = top16(x - hi). err ~2^-16 rel.
__device__ inline void trunc_split(float x, ushort& hi, ushort& lo) {
    uint u = __builtin_bit_cast(uint, x);
    hi = (ushort)(u >> 16);
    float fh = __builtin_bit_cast(float, u & 0xFFFF0000u);
    float fl = x - fh;
    lo = (ushort)(__builtin_bit_cast(uint, fl) >> 16);
}

// ================= CSR build =================

__global__ __launch_bounds__(256)
void deg_count_int_kernel(const int* __restrict__ dst, int* __restrict__ cnt, int E) {
    int e = blockIdx.x * 256 + threadIdx.x;
    if (e < E) atomicAdd(&cnt[dst[e]], 1);
}

__global__ __launch_bounds__(256)
void scan_blocks_kernel(const int* __restrict__ cnt, int* __restrict__ rowptr,
                        int* __restrict__ aux, int M) {
    __shared__ int sdata[256];
    const int base = blockIdx.x * 1024 + threadIdx.x * 4;
    int v[4];
#pragma unroll
    for (int i = 0; i < 4; ++i) v[i] = (base + i < M) ? cnt[base + i] : 0;
    int tsum = v[0] + v[1] + v[2] + v[3];
    sdata[threadIdx.x] = tsum;
    __syncthreads();
    int val = tsum;
    for (int off = 1; off < 256; off <<= 1) {
        int n = (threadIdx.x >= off) ? sdata[threadIdx.x - off] : 0;
        __syncthreads();
        val += n;
        sdata[threadIdx.x] = val;
        __syncthreads();
    }
    int run = val - tsum;
#pragma unroll
    for (int i = 0; i < 4; ++i) {
        if (base + i < M) rowptr[base + i] = run;
        run += v[i];
    }
    if (threadIdx.x == 255) aux[blockIdx.x] = val;
}

__global__ __launch_bounds__(128)
void scan_aux_kernel(int* __restrict__ aux, int n) {
    __shared__ int s[128];
    int v = (threadIdx.x < n) ? aux[threadIdx.x] : 0;
    s[threadIdx.x] = v;
    __syncthreads();
    int val = v;
    for (int off = 1; off < 128; off <<= 1) {
        int nn = (threadIdx.x >= off) ? s[threadIdx.x - off] : 0;
        __syncthreads();
        val += nn;
        s[threadIdx.x] = val;
        __syncthreads();
    }
    if (threadIdx.x < n) aux[threadIdx.x] = val - v;
}

// rowptr/cursor finalize + dis = rsqrt(deg+1)
__global__ __launch_bounds__(256)
void scan_add_kernel(int* __restrict__ rowptr, int* __restrict__ cursor,
                     const int* __restrict__ aux, const int* __restrict__ cnt,
                     float* __restrict__ dis, int M) {
    int i = blockIdx.x * 256 + threadIdx.x;
    if (i >= M) return;
    int v = rowptr[i] + aux[i >> 10];
    rowptr[i] = v;
    cursor[i] = v;
    dis[i] = rsqrtf((float)cnt[i] + 1.0f);
}

__global__ __launch_bounds__(256)
void scatter_kernel(const int* __restrict__ src, const int* __restrict__ dst,
                    const float* __restrict__ dis, int* __restrict__ cursor,
                    int* __restrict__ es, float* __restrict__ ces, int E) {
    int e = blockIdx.x * 256 + threadIdx.x;
    if (e >= E) return;
    int s = src[e], d = dst[e];
    int pos = atomicAdd(&cursor[d], 1);
    es[pos] = s;
    ces[pos] = dis[s];
}

// ================= weight prep: W[k][n] fp32 -> hi/lo bf16, [n][136] padded =================
__global__ __launch_bounds__(256)
void wprep_kernel(const float* __restrict__ W1, const float* __restrict__ W2,
                  const float* __restrict__ W3, const float* __restrict__ W4,
                  const float* __restrict__ W5, ushort* __restrict__ imgs) {
    int w = blockIdx.x >> 6;
    int e = (blockIdx.x & 63) * 256 + threadIdx.x;
    const float* W = w == 0 ? W1 : w == 1 ? W2 : w == 2 ? W3 : w == 3 ? W4 : W5;
    int k = e >> 7, n = e & 127;
    ushort hi, lo;
    trunc_split(W[e], hi, lo);
    ushort* img = imgs + (size_t)w * 34816;
    img[n * 136 + k]         = hi;
    img[17408 + n * 136 + k] = lo;
}

// ================= fused MLP + GCN0-GEMM: 4 layers, one pass (32x32x16, col-split) ==========
// 512 threads = 8 waves; band = wv>>1 (32 rows), ch = wv&1 (64-col half).
// Two waves per band share A rows; each owns 2 N-tiles -> 48 MFMA/wave/layer.
// Single sW buffer (69632B) aliased with fp32 sAct[128][132]; async DMA staging.
// 4 barriers/layer (extra one: act-write -> cross-wave read-back).
__global__ __launch_bounds__(512, 4)
void fused_mlp4_kernel(const float* __restrict__ X, const ushort* __restrict__ imgs,
                       const float* __restrict__ b1, const float* __restrict__ b2,
                       const float* __restrict__ b3, float* __restrict__ Y, int M) {
    __shared__ ushort sW[34816];            // 69632 B, aliased:
    float* sAct = (float*)sW;               //   sAct[128][132] = 67584 B

    const int tid   = threadIdx.x;
    const int lane  = tid & 63;
    const int wv    = tid >> 6;             // 0..7
    const int band  = wv >> 1;              // 0..3 : 32-row band
    const int ch    = wv & 1;               // 0/1  : 64-col half
    const int col32 = lane & 31;
    const int hl    = lane >> 5;
    const int kof8  = hl * 8;
    const int row0  = blockIdx.x * 128;
    const int lrow  = band * 32 + col32;    // A-frag local row

    // ---- layer-0 A fragments from global x: 8 K-slices of 16 ----
    bf16x8 ahi[8], alo[8];
    {
        const int arow = row0 + lrow;
        const bool ok = arow < M;
        const float* ap = X + (size_t)arow * 128 + kof8;
#pragma unroll
        for (int kb = 0; kb < 8; ++kb) {
            float f[8];
            if (ok) {
                float4 f0 = *(const float4*)(ap + kb * 16);
                float4 f1 = *(const float4*)(ap + kb * 16 + 4);
                f[0] = f0.x; f[1] = f0.y; f[2] = f0.z; f[3] = f0.w;
                f[4] = f1.x; f[5] = f1.y; f[6] = f1.z; f[7] = f1.w;
            } else {
#pragma unroll
                for (int e = 0; e < 8; ++e) f[e] = 0.f;
            }
            bf16x8 h, l;
#pragma unroll
            for (int e = 0; e < 8; ++e) {
                ushort hb, lb;
                trunc_split(f[e], hb, lb);
                h[e] = (short)hb; l[e] = (short)lb;
            }
            ahi[kb] = h; alo[kb] = l;
        }
    }

    f32x16 acc[2];
    for (int t = 0; t < 4; ++t) {
        // ---- stage W image t via async DMA (4352 uint4 over 8 waves) ----
        {
            const uint4* g4 = (const uint4*)(imgs + (size_t)t * 34816);
            uint* sW_u = (uint*)sW;
#pragma unroll
            for (int j = 0; j < 9; ++j) {
                int c = j * 512 + wv * 64;
                if (c < 4352) lds_dma16(sW_u + c * 4, g4 + c + lane);
            }
        }
        __syncthreads();                     // DMA drained; sW_t ready

#pragma unroll
        for (int nt = 0; nt < 2; ++nt)
#pragma unroll
            for (int r = 0; r < 16; ++r) acc[nt][r] = 0.f;

#pragma unroll
        for (int kb = 0; kb < 8; ++kb) {
#pragma unroll
            for (int nt = 0; nt < 2; ++nt) {
                const int bcol = ch * 64 + nt * 32 + col32;
                const ushort* ph = &sW[bcol * 136 + kb * 16 + kof8];
                bf16x8 bh = *(const bf16x8*)ph;
                bf16x8 bl = *(const bf16x8*)(ph + 17408);
                acc[nt] = __builtin_amdgcn_mfma_f32_32x32x16_bf16(ahi[kb], bh, acc[nt], 0, 0, 0);
                acc[nt] = __builtin_amdgcn_mfma_f32_32x32x16_bf16(alo[kb], bh, acc[nt], 0, 0, 0);
                acc[nt] = __builtin_amdgcn_mfma_f32_32x32x16_bf16(ahi[kb], bl, acc[nt], 0, 0, 0);
            }
        }

        if (t < 3) {
            __syncthreads();                 // all waves done reading sW_t -> region is sAct now
            const float* bias = t == 0 ? b1 : t == 1 ? b2 : b3;
#pragma unroll
            for (int nt = 0; nt < 2; ++nt) {
                int col = ch * 64 + nt * 32 + col32;
                float bc = bias[col];
#pragma unroll
                for (int r = 0; r < 16; ++r) {
                    float v = acc[nt][r] + bc;
                    v = v > 0.f ? v : 0.01f * v;
                    int crow = (r & 3) + 8 * (r >> 2) + 4 * hl;
                    sAct[(band * 32 + crow) * 132 + col] = v;
                }
            }
            __syncthreads();                 // band's both col-half waves committed
            // read back full-K rows (crosses the two col-half waves of the band)
            float f[8][8];
#pragma unroll
            for (int kb = 0; kb < 8; ++kb) {
                float4 f0 = *(const float4*)&sAct[lrow * 132 + kb * 16 + kof8];
                float4 f1 = *(const float4*)&sAct[lrow * 132 + kb * 16 + kof8 + 4];
                f[kb][0] = f0.x; f[kb][1] = f0.y; f[kb][2] = f0.z; f[kb][3] = f0.w;
                f[kb][4] = f1.x; f[kb][5] = f1.y; f[kb][6] = f1.z; f[kb][7] = f1.w;
            }
#pragma unroll
            for (int kb = 0; kb < 8; ++kb) {
                bf16x8 h, l;
#pragma unroll
                for (int e = 0; e < 8; ++e) {
                    ushort hb, lb;
                    trunc_split(f[kb][e], hb, lb);
                    h[e] = (short)hb; l[e] = (short)lb;
                }
                ahi[kb] = h; alo[kb] = l;
            }
            __syncthreads();                 // sAct reads done before next sW DMA
        } else {
            // final layer (Wg0): raw fp32 out
#pragma unroll
            for (int nt = 0; nt < 2; ++nt) {
                int col = ch * 64 + nt * 32 + col32;
#pragma unroll
                for (int r = 0; r < 16; ++r) {
                    int row = row0 + band * 32 + (r & 3) + 8 * (r >> 2) + 4 * hl;
                    if (row < M) Y[(size_t)row * 128 + col] = acc[nt][r];
                }
            }
        }
    }
}

// ================= GEMM + bias/lrelu/Wo-dot: ho = lrelu(X@Wg1+b)@Wo (32x32x16) =================
// 512 threads = 8 waves x 32-row bands = 256-row tile; W via async DMA; writes only ho.
__global__ __launch_bounds__(512, 4)
void gemm_ho_kernel(const float* __restrict__ X, const ushort* __restrict__ img,
                    const float* __restrict__ bias, const float* __restrict__ Wo,
                    float* __restrict__ ho, int M) {
    __shared__ ushort sB[34816];

    const int tid   = threadIdx.x;
    const int lane  = tid & 63;
    const int wv    = tid >> 6;             // 0..7
    const int col32 = lane & 31;
    const int hl    = lane >> 5;
    const int kof8  = hl * 8;
    const int row0  = blockIdx.x * 256;
    const int lrow  = wv * 32 + col32;

    // stage W via async DMA (4352 uint4 chunks over 8 waves)
    {
        const uint4* g4 = (const uint4*)img;
        uint* sB_u = (uint*)sB;
#pragma unroll
        for (int j = 0; j < 9; ++j) {
            int c = j * 512 + wv * 64;
            if (c < 4352) lds_dma16(sB_u + c * 4, g4 + c + lane);
        }
    }

    // A loads (in flight alongside DMA) + split
    bf16x8 ahi[8], alo[8];
    {
        const int arow = row0 + lrow;
        const bool ok = arow < M;
        const float* ap = X + (size_t)arow * 128 + kof8;
#pragma unroll
        for (int kb = 0; kb < 8; ++kb) {
            float f[8];
            if (ok) {
                float4 f0 = *(const float4*)(ap + kb * 16);
                float4 f1 = *(const float4*)(ap + kb * 16 + 4);
                f[0] = f0.x; f[1] = f0.y; f[2] = f0.z; f[3] = f0.w;
                f[4] = f1.x; f[5] = f1.y; f[6] = f1.z; f[7] = f1.w;
            } else {
#pragma unroll
                for (int e = 0; e < 8; ++e) f[e] = 0.f;
            }
            bf16x8 h, l;
#pragma unroll
            for (int e = 0; e < 8; ++e) {
                ushort hb, lb;
                trunc_split(f[e], hb, lb);
                h[e] = (short)hb; l[e] = (short)lb;
            }
            ahi[kb] = h; alo[kb] = l;
        }
    }
    __syncthreads();

    f32x16 acc[4];
#pragma unroll
    for (int nt = 0; nt < 4; ++nt)
#pragma unroll
        for (int r = 0; r < 16; ++r) acc[nt][r] = 0.f;

#pragma unroll
    for (int kb = 0; kb < 8; ++kb) {
#pragma unroll
        for (int nt = 0; nt < 4; ++nt) {
            const ushort* ph = &sB[(nt * 32 + col32) * 136 + kb * 16 + kof8];
            bf16x8 bh = *(const bf16x8*)ph;
            bf16x8 bl = *(const bf16x8*)(ph + 17408);
            acc[nt] = __builtin_amdgcn_mfma_f32_32x32x16_bf16(ahi[kb], bh, acc[nt], 0, 0, 0);
            acc[nt] = __builtin_amdgcn_mfma_f32_32x32x16_bf16(alo[kb], bh, acc[nt], 0, 0, 0);
            acc[nt] = __builtin_amdgcn_mfma_f32_32x32x16_bf16(ahi[kb], bl, acc[nt], 0, 0, 0);
        }
    }

    // epilogue: part[r] = sum_col lrelu(acc+b)*Wo ; xor-reduce over 32-lane half
    float part[16];
#pragma unroll
    for (int r = 0; r < 16; ++r) part[r] = 0.f;
#pragma unroll
    for (int nt = 0; nt < 4; ++nt) {
        int col = nt * 32 + col32;
        float bc = bias[col];
        float wo = Wo[col];
#pragma unroll
        for (int r = 0; r < 16; ++r) {
            float v = acc[nt][r] + bc;
            v = v > 0.f ? v : 0.01f * v;
            part[r] += v * wo;
        }
    }
#pragma unroll
    for (int m = 1; m < 32; m <<= 1) {
#pragma unroll
        for (int r = 0; r < 16; ++r) part[r] += __shfl_xor(part[r], m, 64);
    }
    if (col32 == 0) {
#pragma unroll
        for (int r = 0; r < 16; ++r) {
            int row = row0 + wv * 32 + (r & 3) + 8 * (r >> 2) + 4 * hl;
            if (row < M) ho[row] = part[r];
        }
    }
}

// ================= GCN aggregation (CSR, HALF-wave per node, float4/lane) ============
// MODE 0: Y[node] = agg (raw)    MODE 1: Y[node] = lrelu(agg + b)
template<int MODE>
__global__ __launch_bounds__(256)
void gcn_agg_csr_kernel(const float* __restrict__ H, const int* __restrict__ es,
                        const float* __restrict__ ces, const int* __restrict__ rowptr,
                        const int* __restrict__ cnt, const float* __restrict__ dis,
                        const float* __restrict__ bias, float* __restrict__ Y, int M) {
    int wid  = (blockIdx.x * 256 + threadIdx.x) >> 6;
    int lane = threadIdx.x & 63;
    int half = lane >> 5;
    int l32  = lane & 31;
    int node = wid * 2 + half;
    if (node >= M) return;

    const float dd  = dis[node];
    const int   beg = rowptr[node];
    const int   n   = cnt[node];

    float4 hv = ((const float4*)H)[(size_t)node * 32 + l32];
    float4 acc;
    acc.x = hv.x * dd * dd; acc.y = hv.y * dd * dd;
    acc.z = hv.z * dd * dd; acc.w = hv.w * dd * dd;

    int j = 0;
    for (; j + 4 <= n; j += 4) {
        int   s0 = es[beg + j],      s1 = es[beg + j + 1];
        int   s2 = es[beg + j + 2],  s3 = es[beg + j + 3];
        float c0 = ces[beg + j] * dd,     c1 = ces[beg + j + 1] * dd;
        float c2 = ces[beg + j + 2] * dd, c3 = ces[beg + j + 3] * dd;
        float4 v0 = ((const float4*)H)[(size_t)s0 * 32 + l32];
        float4 v1 = ((const float4*)H)[(size_t)s1 * 32 + l32];
        float4 v2 = ((const float4*)H)[(size_t)s2 * 32 + l32];
        float4 v3 = ((const float4*)H)[(size_t)s3 * 32 + l32];
        acc.x += c0 * v0.x + c1 * v1.x + c2 * v2.x + c3 * v3.x;
        acc.y += c0 * v0.y + c1 * v1.y + c2 * v2.y + c3 * v3.y;
        acc.z += c0 * v0.z + c1 * v1.z + c2 * v2.z + c3 * v3.z;
        acc.w += c0 * v0.w + c1 * v1.w + c2 * v2.w + c3 * v3.w;
    }
    for (; j < n; ++j) {
        int   s = es[beg + j];
        float c = ces[beg + j] * dd;
        float4 v = ((const float4*)H)[(size_t)s * 32 + l32];
        acc.x += c * v.x; acc.y += c * v.y;
        acc.z += c * v.z; acc.w += c * v.w;
    }

    if (MODE == 1) {
        float4 bb = ((const float4*)bias)[l32];
        acc.x += bb.x; acc.y += bb.y; acc.z += bb.z; acc.w += bb.w;
        acc.x = acc.x > 0.f ? acc.x : 0.01f * acc.x;
        acc.y = acc.y > 0.f ? acc.y : 0.01f * acc.y;
        acc.z = acc.z > 0.f ? acc.z : 0.01f * acc.z;
        acc.w = acc.w > 0.f ? acc.w : 0.01f * acc.w;
    }
    ((float4*)Y)[(size_t)node * 32 + l32] = acc;
}

// ================= output layer scalar aggregation =================
__global__ __launch_bounds__(256)
void out_csr_kernel(const float* __restrict__ ho, const int* __restrict__ es,
                    const float* __restrict__ ces, const int* __restrict__ rowptr,
                    const int* __restrict__ cnt, const float* __restrict__ dis,
                    const float* __restrict__ bo, float* __restrict__ out, int M) {
    int i = blockIdx.x * 256 + threadIdx.x;
    if (i >= M) return;
    float dd  = dis[i];
    float acc = ho[i] * dd * dd;
    int   beg = rowptr[i], n = cnt[i];
    for (int j = 0; j < n; ++j)
        acc += ces[beg + j] * dd * ho[es[beg + j]];
    out[i] = acc + bo[0];
}

// ================= launch =================

extern "C" void kernel_launch(void* const* d_in, const int* in_sizes, int n_in,
                              void* d_out, int out_size, void* d_ws, size_t ws_size,
                              hipStream_t stream) {
    const float* x   = (const float*)d_in[0];
    const int*   ei  = (const int*)d_in[1];
    const float* W1  = (const float*)d_in[2];
    const float* b1  = (const float*)d_in[3];
    const float* W2  = (const float*)d_in[4];
    const float* b2  = (const float*)d_in[5];
    const float* W3  = (const float*)d_in[6];
    const float* b3  = (const float*)d_in[7];
    const float* Wg0 = (const float*)d_in[8];
    const float* bg0 = (const float*)d_in[9];
    const float* Wg1 = (const float*)d_in[10];
    const float* bg1 = (const float*)d_in[11];
    const float* Wo  = (const float*)d_in[12];
    const float* bo  = (const float*)d_in[13];

    const int M = in_sizes[0] / D_H;   // 100000
    const int E = in_sizes[1] / 2;     // 640000
    const int* se = ei;
    const int* de = ei + E;

    // workspace layout
    float*  A      = (float*)d_ws;                   // [M*128]
    float*  B      = A + (size_t)M * D_H;            // [M*128]
    ushort* Wimg   = (ushort*)(B + (size_t)M * D_H); // 5 * 34816 ushorts
    float*  dis    = (float*)(Wimg + 5 * 34816);     // [M]
    float*  ho     = dis + M;                        // [M]
    float*  ces    = ho + M;                         // [E]
    int*    cnt    = (int*)(ces + E);                // [M]
    int*    rowptr = cnt + M;                        // [M]
    int*    cursor = rowptr + M;                     // [M]
    int*    es     = cursor + M;                     // [E]
    int*    aux    = es + E;                         // [128]

    float* out = (float*)d_out;

    const int nChunks     = (M + 1023) / 1024;
    const int gemm_blocks = (M + 127) / 128;
    const int ho_blocks   = (M + 255) / 256;
    const int pair_waves  = ((M + 1) / 2) * 64;
    const int agg_blocks  = (pair_waves + 255) / 256;

    // ---- CSR build + weight prep ----
    hipMemsetAsync(cnt, 0, M * sizeof(int), stream);
    wprep_kernel<<<320, 256, 0, stream>>>(W1, W2, W3, Wg0, Wg1, Wimg);
    deg_count_int_kernel<<<(E + 255) / 256, 256, 0, stream>>>(de, cnt, E);
    scan_blocks_kernel<<<nChunks, 256, 0, stream>>>(cnt, rowptr, aux, M);
    scan_aux_kernel<<<1, 128, 0, stream>>>(aux, nChunks);
    scan_add_kernel<<<(M + 255) / 256, 256, 0, stream>>>(rowptr, cursor, aux, cnt, dis, M);
    scatter_kernel<<<(E + 255) / 256, 256, 0, stream>>>(se, de, dis, cursor, es, ces, E);

    // ---- fused MLP (W1,W2,W3) + GCN0 GEMM (Wg0): x -> B ----
    fused_mlp4_kernel<<<gemm_blocks, 512, 0, stream>>>(x, Wimg, b1, b2, b3, B, M);

    // ---- GCN0 aggregation + bias bg0 + lrelu: B -> A ----
    gcn_agg_csr_kernel<1><<<agg_blocks, 256, 0, stream>>>(B, es, ces, rowptr, cnt, dis, bg0, A, M);

    // ---- GCN1 flipped: raw aggregation A -> B, then GEMM(+bg1+lrelu+Wo dot) -> ho ----
    gcn_agg_csr_kernel<0><<<agg_blocks, 256, 0, stream>>>(A, es, ces, rowptr, cnt, dis, nullptr, B, M);
    gemm_ho_kernel<<<ho_blocks, 512, 0, stream>>>(B, Wimg + 4 * 34816, bg1, Wo, ho, M);

    // ---- GCN2 scalar aggregation ----
    out_csr_kernel<<<(M + 255) / 256, 256, 0, stream>>>(ho, es, ces, rowptr, cnt, dis, bo, out, M);
}

// Round 17
// 376.903 us; speedup vs baseline: 1.0664x; 1.0664x over previous
//
#include <hip/hip_runtime.h>
#include <hip/hip_bf16.h>

#define D_H 128

typedef __attribute__((ext_vector_type(8)))  short bf16x8;
typedef __attribute__((ext_vector_type(16))) float f32x16;

typedef __attribute__((address_space(3))) uint lds_uint;
typedef __attribute__((address_space(1))) const uint glb_uint;

// async 16B/lane global->LDS copy: lds base wave-uniform, gsrc per-lane
__device__ __forceinline__ void lds_dma16(uint* lds_base, const uint4* gsrc) {
    __builtin_amdgcn_global_load_lds((glb_uint*)gsrc, (lds_uint*)lds_base, 16, 0, 0);
}

// truncation hi/lo bf16 split: hi = top16(x), lo = top16(x - hi). err ~2^-16 rel.
__device__ inline void trunc_split(float x, ushort& hi, ushort& lo) {
    uint u = __builtin_bit_cast(uint, x);
    hi = (ushort)(u >> 16);
    float fh = __builtin_bit_cast(float, u & 0xFFFF0000u);
    float fl = x - fh;
    lo = (ushort)(__builtin_bit_cast(uint, fl) >> 16);
}

// ================= CSR build =================

__global__ __launch_bounds__(256)
void deg_count_int_kernel(const int* __restrict__ dst, int* __restrict__ cnt, int E) {
    int e = blockIdx.x * 256 + threadIdx.x;
    if (e < E) atomicAdd(&cnt[dst[e]], 1);
}

__global__ __launch_bounds__(256)
void scan_blocks_kernel(const int* __restrict__ cnt, int* __restrict__ rowptr,
                        int* __restrict__ aux, int M) {
    __shared__ int sdata[256];
    const int base = blockIdx.x * 1024 + threadIdx.x * 4;
    int v[4];
#pragma unroll
    for (int i = 0; i < 4; ++i) v[i] = (base + i < M) ? cnt[base + i] : 0;
    int tsum = v[0] + v[1] + v[2] + v[3];
    sdata[threadIdx.x] = tsum;
    __syncthreads();
    int val = tsum;
    for (int off = 1; off < 256; off <<= 1) {
        int n = (threadIdx.x >= off) ? sdata[threadIdx.x - off] : 0;
        __syncthreads();
        val += n;
        sdata[threadIdx.x] = val;
        __syncthreads();
    }
    int run = val - tsum;
#pragma unroll
    for (int i = 0; i < 4; ++i) {
        if (base + i < M) rowptr[base + i] = run;
        run += v[i];
    }
    if (threadIdx.x == 255) aux[blockIdx.x] = val;
}

__global__ __launch_bounds__(128)
void scan_aux_kernel(int* __restrict__ aux, int n) {
    __shared__ int s[128];
    int v = (threadIdx.x < n) ? aux[threadIdx.x] : 0;
    s[threadIdx.x] = v;
    __syncthreads();
    int val = v;
    for (int off = 1; off < 128; off <<= 1) {
        int nn = (threadIdx.x >= off) ? s[threadIdx.x - off] : 0;
        __syncthreads();
        val += nn;
        s[threadIdx.x] = val;
        __syncthreads();
    }
    if (threadIdx.x < n) aux[threadIdx.x] = val - v;
}

// rowptr/cursor finalize + dis = rsqrt(deg+1)
__global__ __launch_bounds__(256)
void scan_add_kernel(int* __restrict__ rowptr, int* __restrict__ cursor,
                     const int* __restrict__ aux, const int* __restrict__ cnt,
                     float* __restrict__ dis, int M) {
    int i = blockIdx.x * 256 + threadIdx.x;
    if (i >= M) return;
    int v = rowptr[i] + aux[i >> 10];
    rowptr[i] = v;
    cursor[i] = v;
    dis[i] = rsqrtf((float)cnt[i] + 1.0f);
}

__global__ __launch_bounds__(256)
void scatter_kernel(const int* __restrict__ src, const int* __restrict__ dst,
                    const float* __restrict__ dis, int* __restrict__ cursor,
                    int* __restrict__ es, float* __restrict__ ces, int E) {
    int e = blockIdx.x * 256 + threadIdx.x;
    if (e >= E) return;
    int s = src[e], d = dst[e];
    int pos = atomicAdd(&cursor[d], 1);
    es[pos] = s;
    ces[pos] = dis[s];
}

// ================= weight prep: W[k][n] fp32 -> hi/lo bf16, [n][136] padded =================
__global__ __launch_bounds__(256)
void wprep_kernel(const float* __restrict__ W1, const float* __restrict__ W2,
                  const float* __restrict__ W3, const float* __restrict__ W4,
                  const float* __restrict__ W5, ushort* __restrict__ imgs) {
    int w = blockIdx.x >> 6;
    int e = (blockIdx.x & 63) * 256 + threadIdx.x;
    const float* W = w == 0 ? W1 : w == 1 ? W2 : w == 2 ? W3 : w == 3 ? W4 : W5;
    int k = e >> 7, n = e & 127;
    ushort hi, lo;
    trunc_split(W[e], hi, lo);
    ushort* img = imgs + (size_t)w * 34816;
    img[n * 136 + k]         = hi;
    img[17408 + n * 136 + k] = lo;
}

// ================= fused MLP + GCN0-GEMM: 4 layers (32x32x16, col-split, no spill) =========
// 512 threads = 8 waves; band = wv>>1 (32 rows), ch = wv&1 (64-col half).
// acc[2] (32 VGPR) + ahi/alo[8] (32 VGPR); act read-back split per-kb inline (no f[8][8]).
// Single sW buffer (69632B) aliased with fp32 sAct[128][132]; async DMA staging.
__global__ __launch_bounds__(512, 4)
void fused_mlp4_kernel(const float* __restrict__ X, const ushort* __restrict__ imgs,
                       const float* __restrict__ b1, const float* __restrict__ b2,
                       const float* __restrict__ b3, float* __restrict__ Y, int M) {
    __shared__ ushort sW[34816];            // 69632 B, aliased:
    float* sAct = (float*)sW;               //   sAct[128][132] = 67584 B

    const int tid   = threadIdx.x;
    const int lane  = tid & 63;
    const int wv    = tid >> 6;             // 0..7
    const int band  = wv >> 1;              // 0..3 : 32-row band
    const int ch    = wv & 1;               // 0/1  : 64-col half
    const int col32 = lane & 31;
    const int hl    = lane >> 5;
    const int kof8  = hl * 8;
    const int row0  = blockIdx.x * 128;
    const int lrow  = band * 32 + col32;    // A-frag local row

    // ---- layer-0 A fragments from global x: 8 K-slices of 16 ----
    bf16x8 ahi[8], alo[8];
    {
        const int arow = row0 + lrow;
        const bool ok = arow < M;
        const float* ap = X + (size_t)arow * 128 + kof8;
#pragma unroll
        for (int kb = 0; kb < 8; ++kb) {
            float f[8];
            if (ok) {
                float4 f0 = *(const float4*)(ap + kb * 16);
                float4 f1 = *(const float4*)(ap + kb * 16 + 4);
                f[0] = f0.x; f[1] = f0.y; f[2] = f0.z; f[3] = f0.w;
                f[4] = f1.x; f[5] = f1.y; f[6] = f1.z; f[7] = f1.w;
            } else {
#pragma unroll
                for (int e = 0; e < 8; ++e) f[e] = 0.f;
            }
            bf16x8 h, l;
#pragma unroll
            for (int e = 0; e < 8; ++e) {
                ushort hb, lb;
                trunc_split(f[e], hb, lb);
                h[e] = (short)hb; l[e] = (short)lb;
            }
            ahi[kb] = h; alo[kb] = l;
        }
    }

    f32x16 acc[2];
    for (int t = 0; t < 4; ++t) {
        // ---- stage W image t via async DMA (4352 uint4 over 8 waves) ----
        {
            const uint4* g4 = (const uint4*)(imgs + (size_t)t * 34816);
            uint* sW_u = (uint*)sW;
#pragma unroll
            for (int j = 0; j < 9; ++j) {
                int c = j * 512 + wv * 64;
                if (c < 4352) lds_dma16(sW_u + c * 4, g4 + c + lane);
            }
        }
        __syncthreads();                     // DMA drained; sW_t ready

#pragma unroll
        for (int nt = 0; nt < 2; ++nt)
#pragma unroll
            for (int r = 0; r < 16; ++r) acc[nt][r] = 0.f;

#pragma unroll
        for (int kb = 0; kb < 8; ++kb) {
#pragma unroll
            for (int nt = 0; nt < 2; ++nt) {
                const int bcol = ch * 64 + nt * 32 + col32;
                const ushort* ph = &sW[bcol * 136 + kb * 16 + kof8];
                bf16x8 bh = *(const bf16x8*)ph;
                bf16x8 bl = *(const bf16x8*)(ph + 17408);
                acc[nt] = __builtin_amdgcn_mfma_f32_32x32x16_bf16(ahi[kb], bh, acc[nt], 0, 0, 0);
                acc[nt] = __builtin_amdgcn_mfma_f32_32x32x16_bf16(alo[kb], bh, acc[nt], 0, 0, 0);
                acc[nt] = __builtin_amdgcn_mfma_f32_32x32x16_bf16(ahi[kb], bl, acc[nt], 0, 0, 0);
            }
        }

        if (t < 3) {
            __syncthreads();                 // all waves done reading sW_t -> region is sAct now
            const float* bias = t == 0 ? b1 : t == 1 ? b2 : b3;
#pragma unroll
            for (int nt = 0; nt < 2; ++nt) {
                int col = ch * 64 + nt * 32 + col32;
                float bc = bias[col];
#pragma unroll
                for (int r = 0; r < 16; ++r) {
                    float v = acc[nt][r] + bc;
                    v = v > 0.f ? v : 0.01f * v;
                    int crow = (r & 3) + 8 * (r >> 2) + 4 * hl;
                    sAct[(band * 32 + crow) * 132 + col] = v;
                }
            }
            __syncthreads();                 // band's both col-half waves committed
            // read back full-K rows, split per-kb inline (temps die each iteration)
#pragma unroll
            for (int kb = 0; kb < 8; ++kb) {
                float4 f0 = *(const float4*)&sAct[lrow * 132 + kb * 16 + kof8];
                float4 f1 = *(const float4*)&sAct[lrow * 132 + kb * 16 + kof8 + 4];
                float f[8] = {f0.x, f0.y, f0.z, f0.w, f1.x, f1.y, f1.z, f1.w};
                bf16x8 h, l;
#pragma unroll
                for (int e = 0; e < 8; ++e) {
                    ushort hb, lb;
                    trunc_split(f[e], hb, lb);
                    h[e] = (short)hb; l[e] = (short)lb;
                }
                ahi[kb] = h; alo[kb] = l;
            }
            __syncthreads();                 // sAct reads done before next sW DMA
        } else {
            // final layer (Wg0): raw fp32 out
#pragma unroll
            for (int nt = 0; nt < 2; ++nt) {
                int col = ch * 64 + nt * 32 + col32;
#pragma unroll
                for (int r = 0; r < 16; ++r) {
                    int row = row0 + band * 32 + (r & 3) + 8 * (r >> 2) + 4 * hl;
                    if (row < M) Y[(size_t)row * 128 + col] = acc[nt][r];
                }
            }
        }
    }
}

// ================= GEMM + bias/lrelu/Wo-dot: ho = lrelu(X@Wg1+b)@Wo (32x32x16) =================
// 512 threads = 8 waves x 32-row bands = 256-row tile; W via async DMA; writes only ho.
__global__ __launch_bounds__(512, 4)
void gemm_ho_kernel(const float* __restrict__ X, const ushort* __restrict__ img,
                    const float* __restrict__ bias, const float* __restrict__ Wo,
                    float* __restrict__ ho, int M) {
    __shared__ ushort sB[34816];

    const int tid   = threadIdx.x;
    const int lane  = tid & 63;
    const int wv    = tid >> 6;             // 0..7
    const int col32 = lane & 31;
    const int hl    = lane >> 5;
    const int kof8  = hl * 8;
    const int row0  = blockIdx.x * 256;
    const int lrow  = wv * 32 + col32;

    // stage W via async DMA (4352 uint4 chunks over 8 waves)
    {
        const uint4* g4 = (const uint4*)img;
        uint* sB_u = (uint*)sB;
#pragma unroll
        for (int j = 0; j < 9; ++j) {
            int c = j * 512 + wv * 64;
            if (c < 4352) lds_dma16(sB_u + c * 4, g4 + c + lane);
        }
    }

    // A loads (in flight alongside DMA) + split
    bf16x8 ahi[8], alo[8];
    {
        const int arow = row0 + lrow;
        const bool ok = arow < M;
        const float* ap = X + (size_t)arow * 128 + kof8;
#pragma unroll
        for (int kb = 0; kb < 8; ++kb) {
            float f[8];
            if (ok) {
                float4 f0 = *(const float4*)(ap + kb * 16);
                float4 f1 = *(const float4*)(ap + kb * 16 + 4);
                f[0] = f0.x; f[1] = f0.y; f[2] = f0.z; f[3] = f0.w;
                f[4] = f1.x; f[5] = f1.y; f[6] = f1.z; f[7] = f1.w;
            } else {
#pragma unroll
                for (int e = 0; e < 8; ++e) f[e] = 0.f;
            }
            bf16x8 h, l;
#pragma unroll
            for (int e = 0; e < 8; ++e) {
                ushort hb, lb;
                trunc_split(f[e], hb, lb);
                h[e] = (short)hb; l[e] = (short)lb;
            }
            ahi[kb] = h; alo[kb] = l;
        }
    }
    __syncthreads();

    f32x16 acc[4];
#pragma unroll
    for (int nt = 0; nt < 4; ++nt)
#pragma unroll
        for (int r = 0; r < 16; ++r) acc[nt][r] = 0.f;

#pragma unroll
    for (int kb = 0; kb < 8; ++kb) {
#pragma unroll
        for (int nt = 0; nt < 4; ++nt) {
            const ushort* ph = &sB[(nt * 32 + col32) * 136 + kb * 16 + kof8];
            bf16x8 bh = *(const bf16x8*)ph;
            bf16x8 bl = *(const bf16x8*)(ph + 17408);
            acc[nt] = __builtin_amdgcn_mfma_f32_32x32x16_bf16(ahi[kb], bh, acc[nt], 0, 0, 0);
            acc[nt] = __builtin_amdgcn_mfma_f32_32x32x16_bf16(alo[kb], bh, acc[nt], 0, 0, 0);
            acc[nt] = __builtin_amdgcn_mfma_f32_32x32x16_bf16(ahi[kb], bl, acc[nt], 0, 0, 0);
        }
    }

    // epilogue: part[r] = sum_col lrelu(acc+b)*Wo ; xor-reduce over 32-lane half
    float part[16];
#pragma unroll
    for (int r = 0; r < 16; ++r) part[r] = 0.f;
#pragma unroll
    for (int nt = 0; nt < 4; ++nt) {
        int col = nt * 32 + col32;
        float bc = bias[col];
        float wo = Wo[col];
#pragma unroll
        for (int r = 0; r < 16; ++r) {
            float v = acc[nt][r] + bc;
            v = v > 0.f ? v : 0.01f * v;
            part[r] += v * wo;
        }
    }
#pragma unroll
    for (int m = 1; m < 32; m <<= 1) {
#pragma unroll
        for (int r = 0; r < 16; ++r) part[r] += __shfl_xor(part[r], m, 64);
    }
    if (col32 == 0) {
#pragma unroll
        for (int r = 0; r < 16; ++r) {
            int row = row0 + wv * 32 + (r & 3) + 8 * (r >> 2) + 4 * hl;
            if (row < M) ho[row] = part[r];
        }
    }
}

// ================= GCN aggregation (CSR, HALF-wave per node, float4/lane) ============
// MODE 0: Y[node] = agg (raw)    MODE 1: Y[node] = lrelu(agg + b)
template<int MODE>
__global__ __launch_bounds__(256)
void gcn_agg_csr_kernel(const float* __restrict__ H, const int* __restrict__ es,
                        const float* __restrict__ ces, const int* __restrict__ rowptr,
                        const int* __restrict__ cnt, const float* __restrict__ dis,
                        const float* __restrict__ bias, float* __restrict__ Y, int M) {
    int wid  = (blockIdx.x * 256 + threadIdx.x) >> 6;
    int lane = threadIdx.x & 63;
    int half = lane >> 5;
    int l32  = lane & 31;
    int node = wid * 2 + half;
    if (node >= M) return;

    const float dd  = dis[node];
    const int   beg = rowptr[node];
    const int   n   = cnt[node];

    float4 hv = ((const float4*)H)[(size_t)node * 32 + l32];
    float4 acc;
    acc.x = hv.x * dd * dd; acc.y = hv.y * dd * dd;
    acc.z = hv.z * dd * dd; acc.w = hv.w * dd * dd;

    int j = 0;
    for (; j + 4 <= n; j += 4) {
        int   s0 = es[beg + j],      s1 = es[beg + j + 1];
        int   s2 = es[beg + j + 2],  s3 = es[beg + j + 3];
        float c0 = ces[beg + j] * dd,     c1 = ces[beg + j + 1] * dd;
        float c2 = ces[beg + j + 2] * dd, c3 = ces[beg + j + 3] * dd;
        float4 v0 = ((const float4*)H)[(size_t)s0 * 32 + l32];
        float4 v1 = ((const float4*)H)[(size_t)s1 * 32 + l32];
        float4 v2 = ((const float4*)H)[(size_t)s2 * 32 + l32];
        float4 v3 = ((const float4*)H)[(size_t)s3 * 32 + l32];
        acc.x += c0 * v0.x + c1 * v1.x + c2 * v2.x + c3 * v3.x;
        acc.y += c0 * v0.y + c1 * v1.y + c2 * v2.y + c3 * v3.y;
        acc.z += c0 * v0.z + c1 * v1.z + c2 * v2.z + c3 * v3.z;
        acc.w += c0 * v0.w + c1 * v1.w + c2 * v2.w + c3 * v3.w;
    }
    for (; j < n; ++j) {
        int   s = es[beg + j];
        float c = ces[beg + j] * dd;
        float4 v = ((const float4*)H)[(size_t)s * 32 + l32];
        acc.x += c * v.x; acc.y += c * v.y;
        acc.z += c * v.z; acc.w += c * v.w;
    }

    if (MODE == 1) {
        float4 bb = ((const float4*)bias)[l32];
        acc.x += bb.x; acc.y += bb.y; acc.z += bb.z; acc.w += bb.w;
        acc.x = acc.x > 0.f ? acc.x : 0.01f * acc.x;
        acc.y = acc.y > 0.f ? acc.y : 0.01f * acc.y;
        acc.z = acc.z > 0.f ? acc.z : 0.01f * acc.z;
        acc.w = acc.w > 0.f ? acc.w : 0.01f * acc.w;
    }
    ((float4*)Y)[(size_t)node * 32 + l32] = acc;
}

// ================= output layer scalar aggregation =================
__global__ __launch_bounds__(256)
void out_csr_kernel(const float* __restrict__ ho, const int* __restrict__ es,
                    const float* __restrict__ ces, const int* __restrict__ rowptr,
                    const int* __restrict__ cnt, const float* __restrict__ dis,
                    const float* __restrict__ bo, float* __restrict__ out, int M) {
    int i = blockIdx.x * 256 + threadIdx.x;
    if (i >= M) return;
    float dd  = dis[i];
    float acc = ho[i] * dd * dd;
    int   beg = rowptr[i], n = cnt[i];
    for (int j = 0; j < n; ++j)
        acc += ces[beg + j] * dd * ho[es[beg + j]];
    out[i] = acc + bo[0];
}

// ================= launch =================

extern "C" void kernel_launch(void* const* d_in, const int* in_sizes, int n_in,
                              void* d_out, int out_size, void* d_ws, size_t ws_size,
                              hipStream_t stream) {
    const float* x   = (const float*)d_in[0];
    const int*   ei  = (const int*)d_in[1];
    const float* W1  = (const float*)d_in[2];
    const float* b1  = (const float*)d_in[3];
    const float* W2  = (const float*)d_in[4];
    const float* b2  = (const float*)d_in[5];
    const float* W3  = (const float*)d_in[6];
    const float* b3  = (const float*)d_in[7];
    const float* Wg0 = (const float*)d_in[8];
    const float* bg0 = (const float*)d_in[9];
    const float* Wg1 = (const float*)d_in[10];
    const float* bg1 = (const float*)d_in[11];
    const float* Wo  = (const float*)d_in[12];
    const float* bo  = (const float*)d_in[13];

    const int M = in_sizes[0] / D_H;   // 100000
    const int E = in_sizes[1] / 2;     // 640000
    const int* se = ei;
    const int* de = ei + E;

    // workspace layout
    float*  A      = (float*)d_ws;                   // [M*128]
    float*  B      = A + (size_t)M * D_H;            // [M*128]
    ushort* Wimg   = (ushort*)(B + (size_t)M * D_H); // 5 * 34816 ushorts
    float*  dis    = (float*)(Wimg + 5 * 34816);     // [M]
    float*  ho     = dis + M;                        // [M]
    float*  ces    = ho + M;                         // [E]
    int*    cnt    = (int*)(ces + E);                // [M]
    int*    rowptr = cnt + M;                        // [M]
    int*    cursor = rowptr + M;                     // [M]
    int*    es     = cursor + M;                     // [E]
    int*    aux    = es + E;                         // [128]

    float* out = (float*)d_out;

    const int nChunks     = (M + 1023) / 1024;
    const int gemm_blocks = (M + 127) / 128;
    const int ho_blocks   = (M + 255) / 256;
    const int pair_waves  = ((M + 1) / 2) * 64;
    const int agg_blocks  = (pair_waves + 255) / 256;

    // ---- CSR build + weight prep ----
    hipMemsetAsync(cnt, 0, M * sizeof(int), stream);
    wprep_kernel<<<320, 256, 0, stream>>>(W1, W2, W3, Wg0, Wg1, Wimg);
    deg_count_int_kernel<<<(E + 255) / 256, 256, 0, stream>>>(de, cnt, E);
    scan_blocks_kernel<<<nChunks, 256, 0, stream>>>(cnt, rowptr, aux, M);
    scan_aux_kernel<<<1, 128, 0, stream>>>(aux, nChunks);
    scan_add_kernel<<<(M + 255) / 256, 256, 0, stream>>>(rowptr, cursor, aux, cnt, dis, M);
    scatter_kernel<<<(E + 255) / 256, 256, 0, stream>>>(se, de, dis, cursor, es, ces, E);

    // ---- fused MLP (W1,W2,W3) + GCN0 GEMM (Wg0): x -> B ----
    fused_mlp4_kernel<<<gemm_blocks, 512, 0, stream>>>(x, Wimg, b1, b2, b3, B, M);

    // ---- GCN0 aggregation + bias bg0 + lrelu: B -> A ----
    gcn_agg_csr_kernel<1><<<agg_blocks, 256, 0, stream>>>(B, es, ces, rowptr, cnt, dis, bg0, A, M);

    // ---- GCN1 flipped: raw aggregation A -> B, then GEMM(+bg1+lrelu+Wo dot) -> ho ----
    gcn_agg_csr_kernel<0><<<agg_blocks, 256, 0, stream>>>(A, es, ces, rowptr, cnt, dis, nullptr, B, M);
    gemm_ho_kernel<<<ho_blocks, 512, 0, stream>>>(B, Wimg + 4 * 34816, bg1, Wo, ho, M);

    // ---- GCN2 scalar aggregation ----
    out_csr_kernel<<<(M + 255) / 256, 256, 0, stream>>>(ho, es, ces, rowptr, cnt, dis, bo, out, M);
}

// Round 18
// 305.896 us; speedup vs baseline: 1.3140x; 1.2321x over previous
//
#include <hip/hip_runtime.h>
#include <hip/hip_bf16.h>

#define D_H 128

typedef __attribute__((ext_vector_type(8)))  short bf16x8;
typedef __attribute__((ext_vector_type(16))) float f32x16;

typedef __attribute__((address_space(3))) uint lds_uint;
typedef __attribute__((address_space(1))) const uint glb_uint;

// async 16B/lane global->LDS copy: lds base wave-uniform, gsrc per-lane
__device__ __forceinline__ void lds_dma16(uint* lds_base, const uint4* gsrc) {
    __builtin_amdgcn_global_load_lds((glb_uint*)gsrc, (lds_uint*)lds_base, 16, 0, 0);
}

// truncation hi/lo bf16 split: hi = top16(x), lo = top16(x - hi). err ~2^-16 rel.
__device__ inline void trunc_split(float x, ushort& hi, ushort& lo) {
    uint u = __builtin_bit_cast(uint, x);
    hi = (ushort)(u >> 16);
    float fh = __builtin_bit_cast(float, u & 0xFFFF0000u);
    float fl = x - fh;
    lo = (ushort)(__builtin_bit_cast(uint, fl) >> 16);
}

// ================= CSR build =================

__global__ __launch_bounds__(256)
void deg_count_int_kernel(const int* __restrict__ dst, int* __restrict__ cnt, int E) {
    int e = blockIdx.x * 256 + threadIdx.x;
    if (e < E) atomicAdd(&cnt[dst[e]], 1);
}

__global__ __launch_bounds__(256)
void scan_blocks_kernel(const int* __restrict__ cnt, int* __restrict__ rowptr,
                        int* __restrict__ aux, int M) {
    __shared__ int sdata[256];
    const int base = blockIdx.x * 1024 + threadIdx.x * 4;
    int v[4];
#pragma unroll
    for (int i = 0; i < 4; ++i) v[i] = (base + i < M) ? cnt[base + i] : 0;
    int tsum = v[0] + v[1] + v[2] + v[3];
    sdata[threadIdx.x] = tsum;
    __syncthreads();
    int val = tsum;
    for (int off = 1; off < 256; off <<= 1) {
        int n = (threadIdx.x >= off) ? sdata[threadIdx.x - off] : 0;
        __syncthreads();
        val += n;
        sdata[threadIdx.x] = val;
        __syncthreads();
    }
    int run = val - tsum;
#pragma unroll
    for (int i = 0; i < 4; ++i) {
        if (base + i < M) rowptr[base + i] = run;
        run += v[i];
    }
    if (threadIdx.x == 255) aux[blockIdx.x] = val;
}

__global__ __launch_bounds__(128)
void scan_aux_kernel(int* __restrict__ aux, int n) {
    __shared__ int s[128];
    int v = (threadIdx.x < n) ? aux[threadIdx.x] : 0;
    s[threadIdx.x] = v;
    __syncthreads();
    int val = v;
    for (int off = 1; off < 128; off <<= 1) {
        int nn = (threadIdx.x >= off) ? s[threadIdx.x - off] : 0;
        __syncthreads();
        val += nn;
        s[threadIdx.x] = val;
        __syncthreads();
    }
    if (threadIdx.x < n) aux[threadIdx.x] = val - v;
}

// rowptr/cursor finalize + dis = rsqrt(deg+1)
__global__ __launch_bounds__(256)
void scan_add_kernel(int* __restrict__ rowptr, int* __restrict__ cursor,
                     const int* __restrict__ aux, const int* __restrict__ cnt,
                     float* __restrict__ dis, int M) {
    int i = blockIdx.x * 256 + threadIdx.x;
    if (i >= M) return;
    int v = rowptr[i] + aux[i >> 10];
    rowptr[i] = v;
    cursor[i] = v;
    dis[i] = rsqrtf((float)cnt[i] + 1.0f);
}

__global__ __launch_bounds__(256)
void scatter_kernel(const int* __restrict__ src, const int* __restrict__ dst,
                    const float* __restrict__ dis, int* __restrict__ cursor,
                    int* __restrict__ es, float* __restrict__ ces, int E) {
    int e = blockIdx.x * 256 + threadIdx.x;
    if (e >= E) return;
    int s = src[e], d = dst[e];
    int pos = atomicAdd(&cursor[d], 1);
    es[pos] = s;
    ces[pos] = dis[s];
}

// ================= weight prep: W[k][n] fp32 -> hi/lo bf16, [n][136] padded =================
__global__ __launch_bounds__(256)
void wprep_kernel(const float* __restrict__ W1, const float* __restrict__ W2,
                  const float* __restrict__ W3, const float* __restrict__ W4,
                  const float* __restrict__ W5, ushort* __restrict__ imgs) {
    int w = blockIdx.x >> 6;
    int e = (blockIdx.x & 63) * 256 + threadIdx.x;
    const float* W = w == 0 ? W1 : w == 1 ? W2 : w == 2 ? W3 : w == 3 ? W4 : W5;
    int k = e >> 7, n = e & 127;
    ushort hi, lo;
    trunc_split(W[e], hi, lo);
    ushort* img = imgs + (size_t)w * 34816;
    img[n * 136 + k]         = hi;
    img[17408 + n * 136 + k] = lo;
}

// ================= fused MLP + GCN0-GEMM: 4 layers (32x32x16, col-split) =========
// 512 threads = 8 waves; band = wv>>1 (32 rows), ch = wv&1 (64-col half).
// launch_bounds (512,2): VGPR budget ~128 (no forced 64-cap spill); LDS (69632B)
// bounds occupancy at 2 blocks/CU = 16 waves/CU.
__global__ __launch_bounds__(512, 2)
void fused_mlp4_kernel(const float* __restrict__ X, const ushort* __restrict__ imgs,
                       const float* __restrict__ b1, const float* __restrict__ b2,
                       const float* __restrict__ b3, float* __restrict__ Y, int M) {
    __shared__ ushort sW[34816];            // 69632 B, aliased:
    float* sAct = (float*)sW;               //   sAct[128][132] = 67584 B

    const int tid   = threadIdx.x;
    const int lane  = tid & 63;
    const int wv    = tid >> 6;             // 0..7
    const int band  = wv >> 1;              // 0..3 : 32-row band
    const int ch    = wv & 1;               // 0/1  : 64-col half
    const int col32 = lane & 31;
    const int hl    = lane >> 5;
    const int kof8  = hl * 8;
    const int row0  = blockIdx.x * 128;
    const int lrow  = band * 32 + col32;    // A-frag local row

    // ---- layer-0 A fragments from global x: 8 K-slices of 16 ----
    bf16x8 ahi[8], alo[8];
    {
        const int arow = row0 + lrow;
        const bool ok = arow < M;
        const float* ap = X + (size_t)arow * 128 + kof8;
#pragma unroll
        for (int kb = 0; kb < 8; ++kb) {
            float f[8];
            if (ok) {
                float4 f0 = *(const float4*)(ap + kb * 16);
                float4 f1 = *(const float4*)(ap + kb * 16 + 4);
                f[0] = f0.x; f[1] = f0.y; f[2] = f0.z; f[3] = f0.w;
                f[4] = f1.x; f[5] = f1.y; f[6] = f1.z; f[7] = f1.w;
            } else {
#pragma unroll
                for (int e = 0; e < 8; ++e) f[e] = 0.f;
            }
            bf16x8 h, l;
#pragma unroll
            for (int e = 0; e < 8; ++e) {
                ushort hb, lb;
                trunc_split(f[e], hb, lb);
                h[e] = (short)hb; l[e] = (short)lb;
            }
            ahi[kb] = h; alo[kb] = l;
        }
    }

    f32x16 acc[2];
    for (int t = 0; t < 4; ++t) {
        // ---- stage W image t via async DMA (4352 uint4 over 8 waves) ----
        {
            const uint4* g4 = (const uint4*)(imgs + (size_t)t * 34816);
            uint* sW_u = (uint*)sW;
#pragma unroll
            for (int j = 0; j < 9; ++j) {
                int c = j * 512 + wv * 64;
                if (c < 4352) lds_dma16(sW_u + c * 4, g4 + c + lane);
            }
        }
        __syncthreads();                     // DMA drained; sW_t ready

#pragma unroll
        for (int nt = 0; nt < 2; ++nt)
#pragma unroll
            for (int r = 0; r < 16; ++r) acc[nt][r] = 0.f;

#pragma unroll
        for (int kb = 0; kb < 8; ++kb) {
#pragma unroll
            for (int nt = 0; nt < 2; ++nt) {
                const int bcol = ch * 64 + nt * 32 + col32;
                const ushort* ph = &sW[bcol * 136 + kb * 16 + kof8];
                bf16x8 bh = *(const bf16x8*)ph;
                bf16x8 bl = *(const bf16x8*)(ph + 17408);
                acc[nt] = __builtin_amdgcn_mfma_f32_32x32x16_bf16(ahi[kb], bh, acc[nt], 0, 0, 0);
                acc[nt] = __builtin_amdgcn_mfma_f32_32x32x16_bf16(alo[kb], bh, acc[nt], 0, 0, 0);
                acc[nt] = __builtin_amdgcn_mfma_f32_32x32x16_bf16(ahi[kb], bl, acc[nt], 0, 0, 0);
            }
        }

        if (t < 3) {
            __syncthreads();                 // all waves done reading sW_t -> region is sAct now
            const float* bias = t == 0 ? b1 : t == 1 ? b2 : b3;
#pragma unroll
            for (int nt = 0; nt < 2; ++nt) {
                int col = ch * 64 + nt * 32 + col32;
                float bc = bias[col];
#pragma unroll
                for (int r = 0; r < 16; ++r) {
                    float v = acc[nt][r] + bc;
                    v = v > 0.f ? v : 0.01f * v;
                    int crow = (r & 3) + 8 * (r >> 2) + 4 * hl;
                    sAct[(band * 32 + crow) * 132 + col] = v;
                }
            }
            __syncthreads();                 // band's both col-half waves committed
            // read back full-K rows, split per-kb inline (temps die each iteration)
#pragma unroll
            for (int kb = 0; kb < 8; ++kb) {
                float4 f0 = *(const float4*)&sAct[lrow * 132 + kb * 16 + kof8];
                float4 f1 = *(const float4*)&sAct[lrow * 132 + kb * 16 + kof8 + 4];
                float f[8] = {f0.x, f0.y, f0.z, f0.w, f1.x, f1.y, f1.z, f1.w};
                bf16x8 h, l;
#pragma unroll
                for (int e = 0; e < 8; ++e) {
                    ushort hb, lb;
                    trunc_split(f[e], hb, lb);
                    h[e] = (short)hb; l[e] = (short)lb;
                }
                ahi[kb] = h; alo[kb] = l;
            }
            __syncthreads();                 // sAct reads done before next sW DMA
        } else {
            // final layer (Wg0): raw fp32 out
#pragma unroll
            for (int nt = 0; nt < 2; ++nt) {
                int col = ch * 64 + nt * 32 + col32;
#pragma unroll
                for (int r = 0; r < 16; ++r) {
                    int row = row0 + band * 32 + (r & 3) + 8 * (r >> 2) + 4 * hl;
                    if (row < M) Y[(size_t)row * 128 + col] = acc[nt][r];
                }
            }
        }
    }
}

// ================= GEMM + bias/lrelu/Wo-dot: ho = lrelu(X@Wg1+b)@Wo (32x32x16) =================
// 512 threads = 8 waves x 32-row bands = 256-row tile; (512,2) -> no VGPR-cap spill.
__global__ __launch_bounds__(512, 2)
void gemm_ho_kernel(const float* __restrict__ X, const ushort* __restrict__ img,
                    const float* __restrict__ bias, const float* __restrict__ Wo,
                    float* __restrict__ ho, int M) {
    __shared__ ushort sB[34816];

    const int tid   = threadIdx.x;
    const int lane  = tid & 63;
    const int wv    = tid >> 6;             // 0..7
    const int col32 = lane & 31;
    const int hl    = lane >> 5;
    const int kof8  = hl * 8;
    const int row0  = blockIdx.x * 256;
    const int lrow  = wv * 32 + col32;

    // stage W via async DMA (4352 uint4 chunks over 8 waves)
    {
        const uint4* g4 = (const uint4*)img;
        uint* sB_u = (uint*)sB;
#pragma unroll
        for (int j = 0; j < 9; ++j) {
            int c = j * 512 + wv * 64;
            if (c < 4352) lds_dma16(sB_u + c * 4, g4 + c + lane);
        }
    }

    // A loads (in flight alongside DMA) + split
    bf16x8 ahi[8], alo[8];
    {
        const int arow = row0 + lrow;
        const bool ok = arow < M;
        const float* ap = X + (size_t)arow * 128 + kof8;
#pragma unroll
        for (int kb = 0; kb < 8; ++kb) {
            float f[8];
            if (ok) {
                float4 f0 = *(const float4*)(ap + kb * 16);
                float4 f1 = *(const float4*)(ap + kb * 16 + 4);
                f[0] = f0.x; f[1] = f0.y; f[2] = f0.z; f[3] = f0.w;
                f[4] = f1.x; f[5] = f1.y; f[6] = f1.z; f[7] = f1.w;
            } else {
#pragma unroll
                for (int e = 0; e < 8; ++e) f[e] = 0.f;
            }
            bf16x8 h, l;
#pragma unroll
            for (int e = 0; e < 8; ++e) {
                ushort hb, lb;
                trunc_split(f[e], hb, lb);
                h[e] = (short)hb; l[e] = (short)lb;
            }
            ahi[kb] = h; alo[kb] = l;
        }
    }
    __syncthreads();

    f32x16 acc[4];
#pragma unroll
    for (int nt = 0; nt < 4; ++nt)
#pragma unroll
        for (int r = 0; r < 16; ++r) acc[nt][r] = 0.f;

#pragma unroll
    for (int kb = 0; kb < 8; ++kb) {
#pragma unroll
        for (int nt = 0; nt < 4; ++nt) {
            const ushort* ph = &sB[(nt * 32 + col32) * 136 + kb * 16 + kof8];
            bf16x8 bh = *(const bf16x8*)ph;
            bf16x8 bl = *(const bf16x8*)(ph + 17408);
            acc[nt] = __builtin_amdgcn_mfma_f32_32x32x16_bf16(ahi[kb], bh, acc[nt], 0, 0, 0);
            acc[nt] = __builtin_amdgcn_mfma_f32_32x32x16_bf16(alo[kb], bh, acc[nt], 0, 0, 0);
            acc[nt] = __builtin_amdgcn_mfma_f32_32x32x16_bf16(ahi[kb], bl, acc[nt], 0, 0, 0);
        }
    }

    // epilogue: part[r] = sum_col lrelu(acc+b)*Wo ; xor-reduce over 32-lane half
    float part[16];
#pragma unroll
    for (int r = 0; r < 16; ++r) part[r] = 0.f;
#pragma unroll
    for (int nt = 0; nt < 4; ++nt) {
        int col = nt * 32 + col32;
        float bc = bias[col];
        float wo = Wo[col];
#pragma unroll
        for (int r = 0; r < 16; ++r) {
            float v = acc[nt][r] + bc;
            v = v > 0.f ? v : 0.01f * v;
            part[r] += v * wo;
        }
    }
#pragma unroll
    for (int m = 1; m < 32; m <<= 1) {
#pragma unroll
        for (int r = 0; r < 16; ++r) part[r] += __shfl_xor(part[r], m, 64);
    }
    if (col32 == 0) {
#pragma unroll
        for (int r = 0; r < 16; ++r) {
            int row = row0 + wv * 32 + (r & 3) + 8 * (r >> 2) + 4 * hl;
            if (row < M) ho[row] = part[r];
        }
    }
}

// ================= GCN aggregation (CSR, HALF-wave per node, float4/lane) ============
// MODE 0: Y[node] = agg (raw)    MODE 1: Y[node] = lrelu(agg + b)
template<int MODE>
__global__ __launch_bounds__(256)
void gcn_agg_csr_kernel(const float* __restrict__ H, const int* __restrict__ es,
                        const float* __restrict__ ces, const int* __restrict__ rowptr,
                        const int* __restrict__ cnt, const float* __restrict__ dis,
                        const float* __restrict__ bias, float* __restrict__ Y, int M) {
    int wid  = (blockIdx.x * 256 + threadIdx.x) >> 6;
    int lane = threadIdx.x & 63;
    int half = lane >> 5;
    int l32  = lane & 31;
    int node = wid * 2 + half;
    if (node >= M) return;

    const float dd  = dis[node];
    const int   beg = rowptr[node];
    const int   n   = cnt[node];

    float4 hv = ((const float4*)H)[(size_t)node * 32 + l32];
    float4 acc;
    acc.x = hv.x * dd * dd; acc.y = hv.y * dd * dd;
    acc.z = hv.z * dd * dd; acc.w = hv.w * dd * dd;

    int j = 0;
    for (; j + 4 <= n; j += 4) {
        int   s0 = es[beg + j],      s1 = es[beg + j + 1];
        int   s2 = es[beg + j + 2],  s3 = es[beg + j + 3];
        float c0 = ces[beg + j] * dd,     c1 = ces[beg + j + 1] * dd;
        float c2 = ces[beg + j + 2] * dd, c3 = ces[beg + j + 3] * dd;
        float4 v0 = ((const float4*)H)[(size_t)s0 * 32 + l32];
        float4 v1 = ((const float4*)H)[(size_t)s1 * 32 + l32];
        float4 v2 = ((const float4*)H)[(size_t)s2 * 32 + l32];
        float4 v3 = ((const float4*)H)[(size_t)s3 * 32 + l32];
        acc.x += c0 * v0.x + c1 * v1.x + c2 * v2.x + c3 * v3.x;
        acc.y += c0 * v0.y + c1 * v1.y + c2 * v2.y + c3 * v3.y;
        acc.z += c0 * v0.z + c1 * v1.z + c2 * v2.z + c3 * v3.z;
        acc.w += c0 * v0.w + c1 * v1.w + c2 * v2.w + c3 * v3.w;
    }
    for (; j < n; ++j) {
        int   s = es[beg + j];
        float c = ces[beg + j] * dd;
        float4 v = ((const float4*)H)[(size_t)s * 32 + l32];
        acc.x += c * v.x; acc.y += c * v.y;
        acc.z += c * v.z; acc.w += c * v.w;
    }

    if (MODE == 1) {
        float4 bb = ((const float4*)bias)[l32];
        acc.x += bb.x; acc.y += bb.y; acc.z += bb.z; acc.w += bb.w;
        acc.x = acc.x > 0.f ? acc.x : 0.01f * acc.x;
        acc.y = acc.y > 0.f ? acc.y : 0.01f * acc.y;
        acc.z = acc.z > 0.f ? acc.z : 0.01f * acc.z;
        acc.w = acc.w > 0.f ? acc.w : 0.01f * acc.w;
    }
    ((float4*)Y)[(size_t)node * 32 + l32] = acc;
}

// ================= output layer scalar aggregation =================
__global__ __launch_bounds__(256)
void out_csr_kernel(const float* __restrict__ ho, const int* __restrict__ es,
                    const float* __restrict__ ces, const int* __restrict__ rowptr,
                    const int* __restrict__ cnt, const float* __restrict__ dis,
                    const float* __restrict__ bo, float* __restrict__ out, int M) {
    int i = blockIdx.x * 256 + threadIdx.x;
    if (i >= M) return;
    float dd  = dis[i];
    float acc = ho[i] * dd * dd;
    int   beg = rowptr[i], n = cnt[i];
    for (int j = 0; j < n; ++j)
        acc += ces[beg + j] * dd * ho[es[beg + j]];
    out[i] = acc + bo[0];
}

// ================= launch =================

extern "C" void kernel_launch(void* const* d_in, const int* in_sizes, int n_in,
                              void* d_out, int out_size, void* d_ws, size_t ws_size,
                              hipStream_t stream) {
    const float* x   = (const float*)d_in[0];
    const int*   ei  = (const int*)d_in[1];
    const float* W1  = (const float*)d_in[2];
    const float* b1  = (const float*)d_in[3];
    const float* W2  = (const float*)d_in[4];
    const float* b2  = (const float*)d_in[5];
    const float* W3  = (const float*)d_in[6];
    const float* b3  = (const float*)d_in[7];
    const float* Wg0 = (const float*)d_in[8];
    const float* bg0 = (const float*)d_in[9];
    const float* Wg1 = (const float*)d_in[10];
    const float* bg1 = (const float*)d_in[11];
    const float* Wo  = (const float*)d_in[12];
    const float* bo  = (const float*)d_in[13];

    const int M = in_sizes[0] / D_H;   // 100000
    const int E = in_sizes[1] / 2;     // 640000
    const int* se = ei;
    const int* de = ei + E;

    // workspace layout
    float*  A      = (float*)d_ws;                   // [M*128]
    float*  B      = A + (size_t)M * D_H;            // [M*128]
    ushort* Wimg   = (ushort*)(B + (size_t)M * D_H); // 5 * 34816 ushorts
    float*  dis    = (float*)(Wimg + 5 * 34816);     // [M]
    float*  ho     = dis + M;                        // [M]
    float*  ces    = ho + M;                         // [E]
    int*    cnt    = (int*)(ces + E);                // [M]
    int*    rowptr = cnt + M;                        // [M]
    int*    cursor = rowptr + M;                     // [M]
    int*    es     = cursor + M;                     // [E]
    int*    aux    = es + E;                         // [128]

    float* out = (float*)d_out;

    const int nChunks     = (M + 1023) / 1024;
    const int gemm_blocks = (M + 127) / 128;
    const int ho_blocks   = (M + 255) / 256;
    const int pair_waves  = ((M + 1) / 2) * 64;
    const int agg_blocks  = (pair_waves + 255) / 256;

    // ---- CSR build + weight prep ----
    hipMemsetAsync(cnt, 0, M * sizeof(int), stream);
    wprep_kernel<<<320, 256, 0, stream>>>(W1, W2, W3, Wg0, Wg1, Wimg);
    deg_count_int_kernel<<<(E + 255) / 256, 256, 0, stream>>>(de, cnt, E);
    scan_blocks_kernel<<<nChunks, 256, 0, stream>>>(cnt, rowptr, aux, M);
    scan_aux_kernel<<<1, 128, 0, stream>>>(aux, nChunks);
    scan_add_kernel<<<(M + 255) / 256, 256, 0, stream>>>(rowptr, cursor, aux, cnt, dis, M);
    scatter_kernel<<<(E + 255) / 256, 256, 0, stream>>>(se, de, dis, cursor, es, ces, E);

    // ---- fused MLP (W1,W2,W3) + GCN0 GEMM (Wg0): x -> B ----
    fused_mlp4_kernel<<<gemm_blocks, 512, 0, stream>>>(x, Wimg, b1, b2, b3, B, M);

    // ---- GCN0 aggregation + bias bg0 + lrelu: B -> A ----
    gcn_agg_csr_kernel<1><<<agg_blocks, 256, 0, stream>>>(B, es, ces, rowptr, cnt, dis, bg0, A, M);

    // ---- GCN1 flipped: raw aggregation A -> B, then GEMM(+bg1+lrelu+Wo dot) -> ho ----
    gcn_agg_csr_kernel<0><<<agg_blocks, 256, 0, stream>>>(A, es, ces, rowptr, cnt, dis, nullptr, B, M);
    gemm_ho_kernel<<<ho_blocks, 512, 0, stream>>>(B, Wimg + 4 * 34816, bg1, Wo, ho, M);

    // ---- GCN2 scalar aggregation ----
    out_csr_kernel<<<(M + 255) / 256, 256, 0, stream>>>(ho, es, ces, rowptr, cnt, dis, bo, out, M);
}

// Round 19
// 283.610 us; speedup vs baseline: 1.4172x; 1.0786x over previous
//
#include <hip/hip_runtime.h>
#include <hip/hip_bf16.h>

#define D_H 128

typedef __attribute__((ext_vector_type(8)))  short bf16x8;
typedef __attribute__((ext_vector_type(16))) float f32x16;

typedef __attribute__((address_space(3))) uint lds_uint;
typedef __attribute__((address_space(1))) const uint glb_uint;

// async 16B/lane global->LDS copy: lds base wave-uniform, gsrc per-lane
__device__ __forceinline__ void lds_dma16(uint* lds_base, const uint4* gsrc) {
    __builtin_amdgcn_global_load_lds((glb_uint*)gsrc, (lds_uint*)lds_base, 16, 0, 0);
}

// truncation hi/lo bf16 split: hi = top16(x), lo = top16(x - hi). err ~2^-16 rel.
__device__ inline void trunc_split(float x, ushort& hi, ushort& lo) {
    uint u = __builtin_bit_cast(uint, x);
    hi = (ushort)(u >> 16);
    float fh = __builtin_bit_cast(float, u & 0xFFFF0000u);
    float fl = x - fh;
    lo = (ushort)(__builtin_bit_cast(uint, fl) >> 16);
}

// ================= CSR build =================

__global__ __launch_bounds__(256)
void deg_count_int_kernel(const int* __restrict__ dst, int* __restrict__ cnt, int E) {
    int e = blockIdx.x * 256 + threadIdx.x;
    if (e < E) atomicAdd(&cnt[dst[e]], 1);
}

__global__ __launch_bounds__(256)
void scan_blocks_kernel(const int* __restrict__ cnt, int* __restrict__ rowptr,
                        int* __restrict__ aux, int M) {
    __shared__ int sdata[256];
    const int base = blockIdx.x * 1024 + threadIdx.x * 4;
    int v[4];
#pragma unroll
    for (int i = 0; i < 4; ++i) v[i] = (base + i < M) ? cnt[base + i] : 0;
    int tsum = v[0] + v[1] + v[2] + v[3];
    sdata[threadIdx.x] = tsum;
    __syncthreads();
    int val = tsum;
    for (int off = 1; off < 256; off <<= 1) {
        int n = (threadIdx.x >= off) ? sdata[threadIdx.x - off] : 0;
        __syncthreads();
        val += n;
        sdata[threadIdx.x] = val;
        __syncthreads();
    }
    int run = val - tsum;
#pragma unroll
    for (int i = 0; i < 4; ++i) {
        if (base + i < M) rowptr[base + i] = run;
        run += v[i];
    }
    if (threadIdx.x == 255) aux[blockIdx.x] = val;
}

__global__ __launch_bounds__(128)
void scan_aux_kernel(int* __restrict__ aux, int n) {
    __shared__ int s[128];
    int v = (threadIdx.x < n) ? aux[threadIdx.x] : 0;
    s[threadIdx.x] = v;
    __syncthreads();
    int val = v;
    for (int off = 1; off < 128; off <<= 1) {
        int nn = (threadIdx.x >= off) ? s[threadIdx.x - off] : 0;
        __syncthreads();
        val += nn;
        s[threadIdx.x] = val;
        __syncthreads();
    }
    if (threadIdx.x < n) aux[threadIdx.x] = val - v;
}

// rowptr/cursor finalize + dis = rsqrt(deg+1)
__global__ __launch_bounds__(256)
void scan_add_kernel(int* __restrict__ rowptr, int* __restrict__ cursor,
                     const int* __restrict__ aux, const int* __restrict__ cnt,
                     float* __restrict__ dis, int M) {
    int i = blockIdx.x * 256 + threadIdx.x;
    if (i >= M) return;
    int v = rowptr[i] + aux[i >> 10];
    rowptr[i] = v;
    cursor[i] = v;
    dis[i] = rsqrtf((float)cnt[i] + 1.0f);
}

__global__ __launch_bounds__(256)
void scatter_kernel(const int* __restrict__ src, const int* __restrict__ dst,
                    const float* __restrict__ dis, int* __restrict__ cursor,
                    int* __restrict__ es, float* __restrict__ ces, int E) {
    int e = blockIdx.x * 256 + threadIdx.x;
    if (e >= E) return;
    int s = src[e], d = dst[e];
    int pos = atomicAdd(&cursor[d], 1);
    es[pos] = s;
    ces[pos] = dis[s];
}

// ================= weight prep: W[k][n] fp32 -> hi/lo bf16, [n][136] padded =================
__global__ __launch_bounds__(256)
void wprep_kernel(const float* __restrict__ W1, const float* __restrict__ W2,
                  const float* __restrict__ W3, const float* __restrict__ W4,
                  const float* __restrict__ W5, ushort* __restrict__ imgs) {
    int w = blockIdx.x >> 6;
    int e = (blockIdx.x & 63) * 256 + threadIdx.x;
    const float* W = w == 0 ? W1 : w == 1 ? W2 : w == 2 ? W3 : w == 3 ? W4 : W5;
    int k = e >> 7, n = e & 127;
    ushort hi, lo;
    trunc_split(W[e], hi, lo);
    ushort* img = imgs + (size_t)w * 34816;
    img[n * 136 + k]         = hi;
    img[17408 + n * 136 + k] = lo;
}

// ================= fused MLP + GCN0-GEMM: 4 layers, one pass (32x32x16 MFMA) =================
// R14-proven structure: 256 threads = 4 waves x 32-row bands; single sW buffer
// (69632B) aliased with fp32 sAct[128][132]; async DMA W staging.
__global__ __launch_bounds__(256, 2)
void fused_mlp4_kernel(const float* __restrict__ X, const ushort* __restrict__ imgs,
                       const float* __restrict__ b1, const float* __restrict__ b2,
                       const float* __restrict__ b3, float* __restrict__ Y, int M) {
    __shared__ ushort sW[34816];            // 69632 B, aliased:
    float* sAct = (float*)sW;               //   sAct[128][132] = 67584 B

    const int tid   = threadIdx.x;
    const int lane  = tid & 63;
    const int wv    = tid >> 6;             // 0..3
    const int col32 = lane & 31;            // W col within 32-tile / A row within band
    const int hl    = lane >> 5;            // 0/1
    const int kof8  = hl * 8;               // k offset within K=16 slice
    const int row0  = blockIdx.x * 128;
    const int lrow  = wv * 32 + col32;      // A-frag local row (wave-private band)

    // ---- layer-0 A fragments from global x: 8 K-slices of 16 ----
    bf16x8 ahi[8], alo[8];
    {
        const int arow = row0 + lrow;
        const bool ok = arow < M;
        const float* ap = X + (size_t)arow * 128 + kof8;
#pragma unroll
        for (int kb = 0; kb < 8; ++kb) {
            float f[8];
            if (ok) {
                float4 f0 = *(const float4*)(ap + kb * 16);
                float4 f1 = *(const float4*)(ap + kb * 16 + 4);
                f[0] = f0.x; f[1] = f0.y; f[2] = f0.z; f[3] = f0.w;
                f[4] = f1.x; f[5] = f1.y; f[6] = f1.z; f[7] = f1.w;
            } else {
#pragma unroll
                for (int e = 0; e < 8; ++e) f[e] = 0.f;
            }
            bf16x8 h, l;
#pragma unroll
            for (int e = 0; e < 8; ++e) {
                ushort hb, lb;
                trunc_split(f[e], hb, lb);
                h[e] = (short)hb; l[e] = (short)lb;
            }
            ahi[kb] = h; alo[kb] = l;
        }
    }

    f32x16 acc[4];
    for (int t = 0; t < 4; ++t) {
        // ---- stage W image t via async DMA (17 chunks/wave, all in flight) ----
        {
            const uint4* g4 = (const uint4*)(imgs + (size_t)t * 34816);
            uint* sW_u = (uint*)sW;
#pragma unroll
            for (int j = 0; j < 17; ++j) {
                int c = j * 256 + wv * 64;              // uint4 chunk base (wave-uniform)
                lds_dma16(sW_u + c * 4, g4 + c + lane);
            }
        }
        __syncthreads();                     // DMA drained; sW_t ready

#pragma unroll
        for (int nt = 0; nt < 4; ++nt)
#pragma unroll
            for (int r = 0; r < 16; ++r) acc[nt][r] = 0.f;

#pragma unroll
        for (int kb = 0; kb < 8; ++kb) {
#pragma unroll
            for (int nt = 0; nt < 4; ++nt) {
                const ushort* ph = &sW[(nt * 32 + col32) * 136 + kb * 16 + kof8];
                bf16x8 bh = *(const bf16x8*)ph;
                bf16x8 bl = *(const bf16x8*)(ph + 17408);
                acc[nt] = __builtin_amdgcn_mfma_f32_32x32x16_bf16(ahi[kb], bh, acc[nt], 0, 0, 0);
                acc[nt] = __builtin_amdgcn_mfma_f32_32x32x16_bf16(alo[kb], bh, acc[nt], 0, 0, 0);
                acc[nt] = __builtin_amdgcn_mfma_f32_32x32x16_bf16(ahi[kb], bl, acc[nt], 0, 0, 0);
            }
        }

        if (t < 3) {
            __syncthreads();                 // all waves done reading sW_t -> region is sAct now
            const float* bias = t == 0 ? b1 : t == 1 ? b2 : b3;
#pragma unroll
            for (int nt = 0; nt < 4; ++nt) {
                int col = nt * 32 + col32;
                float bc = bias[col];
#pragma unroll
                for (int r = 0; r < 16; ++r) {
                    float v = acc[nt][r] + bc;
                    v = v > 0.f ? v : 0.01f * v;
                    int crow = (r & 3) + 8 * (r >> 2) + 4 * hl;
                    sAct[(wv * 32 + crow) * 132 + col] = v;
                }
            }
            // wave-private read-back (same wave wrote these rows)
#pragma unroll
            for (int kb = 0; kb < 8; ++kb) {
                float4 f0 = *(const float4*)&sAct[lrow * 132 + kb * 16 + kof8];
                float4 f1 = *(const float4*)&sAct[lrow * 132 + kb * 16 + kof8 + 4];
                float f[8] = {f0.x, f0.y, f0.z, f0.w, f1.x, f1.y, f1.z, f1.w};
                bf16x8 h, l;
#pragma unroll
                for (int e = 0; e < 8; ++e) {
                    ushort hb, lb;
                    trunc_split(f[e], hb, lb);
                    h[e] = (short)hb; l[e] = (short)lb;
                }
                ahi[kb] = h; alo[kb] = l;
            }
            __syncthreads();                 // sAct reads done before next sW DMA
        } else {
            // final layer (Wg0): raw fp32 out
#pragma unroll
            for (int nt = 0; nt < 4; ++nt) {
                int col = nt * 32 + col32;
#pragma unroll
                for (int r = 0; r < 16; ++r) {
                    int row = row0 + wv * 32 + (r & 3) + 8 * (r >> 2) + 4 * hl;
                    if (row < M) Y[(size_t)row * 128 + col] = acc[nt][r];
                }
            }
        }
    }
}

// ================= GEMM + bias/lrelu/Wo-dot: ho = lrelu(X@Wg1+b)@Wo (32x32x16) =================
// 512 threads = 8 waves x 32-row bands = 256-row tile; (512,2): no 64-VGPR cap spill.
__global__ __launch_bounds__(512, 2)
void gemm_ho_kernel(const float* __restrict__ X, const ushort* __restrict__ img,
                    const float* __restrict__ bias, const float* __restrict__ Wo,
                    float* __restrict__ ho, int M) {
    __shared__ ushort sB[34816];

    const int tid   = threadIdx.x;
    const int lane  = tid & 63;
    const int wv    = tid >> 6;             // 0..7
    const int col32 = lane & 31;
    const int hl    = lane >> 5;
    const int kof8  = hl * 8;
    const int row0  = blockIdx.x * 256;
    const int lrow  = wv * 32 + col32;

    // stage W via async DMA (4352 uint4 chunks over 8 waves)
    {
        const uint4* g4 = (const uint4*)img;
        uint* sB_u = (uint*)sB;
#pragma unroll
        for (int j = 0; j < 9; ++j) {
            int c = j * 512 + wv * 64;
            if (c < 4352) lds_dma16(sB_u + c * 4, g4 + c + lane);
        }
    }

    // A loads (in flight alongside DMA) + split
    bf16x8 ahi[8], alo[8];
    {
        const int arow = row0 + lrow;
        const bool ok = arow < M;
        const float* ap = X + (size_t)arow * 128 + kof8;
#pragma unroll
        for (int kb = 0; kb < 8; ++kb) {
            float f[8];
            if (ok) {
                float4 f0 = *(const float4*)(ap + kb * 16);
                float4 f1 = *(const float4*)(ap + kb * 16 + 4);
                f[0] = f0.x; f[1] = f0.y; f[2] = f0.z; f[3] = f0.w;
                f[4] = f1.x; f[5] = f1.y; f[6] = f1.z; f[7] = f1.w;
            } else {
#pragma unroll
                for (int e = 0; e < 8; ++e) f[e] = 0.f;
            }
            bf16x8 h, l;
#pragma unroll
            for (int e = 0; e < 8; ++e) {
                ushort hb, lb;
                trunc_split(f[e], hb, lb);
                h[e] = (short)hb; l[e] = (short)lb;
            }
            ahi[kb] = h; alo[kb] = l;
        }
    }
    __syncthreads();

    f32x16 acc[4];
#pragma unroll
    for (int nt = 0; nt < 4; ++nt)
#pragma unroll
        for (int r = 0; r < 16; ++r) acc[nt][r] = 0.f;

#pragma unroll
    for (int kb = 0; kb < 8; ++kb) {
#pragma unroll
        for (int nt = 0; nt < 4; ++nt) {
            const ushort* ph = &sB[(nt * 32 + col32) * 136 + kb * 16 + kof8];
            bf16x8 bh = *(const bf16x8*)ph;
            bf16x8 bl = *(const bf16x8*)(ph + 17408);
            acc[nt] = __builtin_amdgcn_mfma_f32_32x32x16_bf16(ahi[kb], bh, acc[nt], 0, 0, 0);
            acc[nt] = __builtin_amdgcn_mfma_f32_32x32x16_bf16(alo[kb], bh, acc[nt], 0, 0, 0);
            acc[nt] = __builtin_amdgcn_mfma_f32_32x32x16_bf16(ahi[kb], bl, acc[nt], 0, 0, 0);
        }
    }

    // epilogue: part[r] = sum_col lrelu(acc+b)*Wo ; xor-reduce over 32-lane half
    float part[16];
#pragma unroll
    for (int r = 0; r < 16; ++r) part[r] = 0.f;
#pragma unroll
    for (int nt = 0; nt < 4; ++nt) {
        int col = nt * 32 + col32;
        float bc = bias[col];
        float wo = Wo[col];
#pragma unroll
        for (int r = 0; r < 16; ++r) {
            float v = acc[nt][r] + bc;
            v = v > 0.f ? v : 0.01f * v;
            part[r] += v * wo;
        }
    }
#pragma unroll
    for (int m = 1; m < 32; m <<= 1) {
#pragma unroll
        for (int r = 0; r < 16; ++r) part[r] += __shfl_xor(part[r], m, 64);
    }
    if (col32 == 0) {
#pragma unroll
        for (int r = 0; r < 16; ++r) {
            int row = row0 + wv * 32 + (r & 3) + 8 * (r >> 2) + 4 * hl;
            if (row < M) ho[row] = part[r];
        }
    }
}

// ================= GCN aggregation (CSR, HALF-wave per node, float4/lane) ============
// MODE 0: Y[node] = agg (raw)    MODE 1: Y[node] = lrelu(agg + b)
template<int MODE>
__global__ __launch_bounds__(256)
void gcn_agg_csr_kernel(const float* __restrict__ H, const int* __restrict__ es,
                        const float* __restrict__ ces, const int* __restrict__ rowptr,
                        const int* __restrict__ cnt, const float* __restrict__ dis,
                        const float* __restrict__ bias, float* __restrict__ Y, int M) {
    int wid  = (blockIdx.x * 256 + threadIdx.x) >> 6;
    int lane = threadIdx.x & 63;
    int half = lane >> 5;
    int l32  = lane & 31;
    int node = wid * 2 + half;
    if (node >= M) return;

    const float dd  = dis[node];
    const int   beg = rowptr[node];
    const int   n   = cnt[node];

    float4 hv = ((const float4*)H)[(size_t)node * 32 + l32];
    float4 acc;
    acc.x = hv.x * dd * dd; acc.y = hv.y * dd * dd;
    acc.z = hv.z * dd * dd; acc.w = hv.w * dd * dd;

    int j = 0;
    for (; j + 4 <= n; j += 4) {
        int   s0 = es[beg + j],      s1 = es[beg + j + 1];
        int   s2 = es[beg + j + 2],  s3 = es[beg + j + 3];
        float c0 = ces[beg + j] * dd,     c1 = ces[beg + j + 1] * dd;
        float c2 = ces[beg + j + 2] * dd, c3 = ces[beg + j + 3] * dd;
        float4 v0 = ((const float4*)H)[(size_t)s0 * 32 + l32];
        float4 v1 = ((const float4*)H)[(size_t)s1 * 32 + l32];
        float4 v2 = ((const float4*)H)[(size_t)s2 * 32 + l32];
        float4 v3 = ((const float4*)H)[(size_t)s3 * 32 + l32];
        acc.x += c0 * v0.x + c1 * v1.x + c2 * v2.x + c3 * v3.x;
        acc.y += c0 * v0.y + c1 * v1.y + c2 * v2.y + c3 * v3.y;
        acc.z += c0 * v0.z + c1 * v1.z + c2 * v2.z + c3 * v3.z;
        acc.w += c0 * v0.w + c1 * v1.w + c2 * v2.w + c3 * v3.w;
    }
    for (; j < n; ++j) {
        int   s = es[beg + j];
        float c = ces[beg + j] * dd;
        float4 v = ((const float4*)H)[(size_t)s * 32 + l32];
        acc.x += c * v.x; acc.y += c * v.y;
        acc.z += c * v.z; acc.w += c * v.w;
    }

    if (MODE == 1) {
        float4 bb = ((const float4*)bias)[l32];
        acc.x += bb.x; acc.y += bb.y; acc.z += bb.z; acc.w += bb.w;
        acc.x = acc.x > 0.f ? acc.x : 0.01f * acc.x;
        acc.y = acc.y > 0.f ? acc.y : 0.01f * acc.y;
        acc.z = acc.z > 0.f ? acc.z : 0.01f * acc.z;
        acc.w = acc.w > 0.f ? acc.w : 0.01f * acc.w;
    }
    ((float4*)Y)[(size_t)node * 32 + l32] = acc;
}

// ================= output layer scalar aggregation =================
__global__ __launch_bounds__(256)
void out_csr_kernel(const float* __restrict__ ho, const int* __restrict__ es,
                    const float* __restrict__ ces, const int* __restrict__ rowptr,
                    const int* __restrict__ cnt, const float* __restrict__ dis,
                    const float* __restrict__ bo, float* __restrict__ out, int M) {
    int i = blockIdx.x * 256 + threadIdx.x;
    if (i >= M) return;
    float dd  = dis[i];
    float acc = ho[i] * dd * dd;
    int   beg = rowptr[i], n = cnt[i];
    for (int j = 0; j < n; ++j)
        acc += ces[beg + j] * dd * ho[es[beg + j]];
    out[i] = acc + bo[0];
}

// ================= launch =================

extern "C" void kernel_launch(void* const* d_in, const int* in_sizes, int n_in,
                              void* d_out, int out_size, void* d_ws, size_t ws_size,
                              hipStream_t stream) {
    const float* x   = (const float*)d_in[0];
    const int*   ei  = (const int*)d_in[1];
    const float* W1  = (const float*)d_in[2];
    const float* b1  = (const float*)d_in[3];
    const float* W2  = (const float*)d_in[4];
    const float* b2  = (const float*)d_in[5];
    const float* W3  = (const float*)d_in[6];
    const float* b3  = (const float*)d_in[7];
    const float* Wg0 = (const float*)d_in[8];
    const float* bg0 = (const float*)d_in[9];
    const float* Wg1 = (const float*)d_in[10];
    const float* bg1 = (const float*)d_in[11];
    const float* Wo  = (const float*)d_in[12];
    const float* bo  = (const float*)d_in[13];

    const int M = in_sizes[0] / D_H;   // 100000
    const int E = in_sizes[1] / 2;     // 640000
    const int* se = ei;
    const int* de = ei + E;

    // workspace layout
    float*  A      = (float*)d_ws;                   // [M*128]
    float*  B      = A + (size_t)M * D_H;            // [M*128]
    ushort* Wimg   = (ushort*)(B + (size_t)M * D_H); // 5 * 34816 ushorts
    float*  dis    = (float*)(Wimg + 5 * 34816);     // [M]
    float*  ho     = dis + M;                        // [M]
    float*  ces    = ho + M;                         // [E]
    int*    cnt    = (int*)(ces + E);                // [M]
    int*    rowptr = cnt + M;                        // [M]
    int*    cursor = rowptr + M;                     // [M]
    int*    es     = cursor + M;                     // [E]
    int*    aux    = es + E;                         // [128]

    float* out = (float*)d_out;

    const int nChunks     = (M + 1023) / 1024;
    const int gemm_blocks = (M + 127) / 128;
    const int ho_blocks   = (M + 255) / 256;
    const int pair_waves  = ((M + 1) / 2) * 64;
    const int agg_blocks  = (pair_waves + 255) / 256;

    // ---- CSR build + weight prep ----
    hipMemsetAsync(cnt, 0, M * sizeof(int), stream);
    wprep_kernel<<<320, 256, 0, stream>>>(W1, W2, W3, Wg0, Wg1, Wimg);
    deg_count_int_kernel<<<(E + 255) / 256, 256, 0, stream>>>(de, cnt, E);
    scan_blocks_kernel<<<nChunks, 256, 0, stream>>>(cnt, rowptr, aux, M);
    scan_aux_kernel<<<1, 128, 0, stream>>>(aux, nChunks);
    scan_add_kernel<<<(M + 255) / 256, 256, 0, stream>>>(rowptr, cursor, aux, cnt, dis, M);
    scatter_kernel<<<(E + 255) / 256, 256, 0, stream>>>(se, de, dis, cursor, es, ces, E);

    // ---- fused MLP (W1,W2,W3) + GCN0 GEMM (Wg0): x -> B ----
    fused_mlp4_kernel<<<gemm_blocks, 256, 0, stream>>>(x, Wimg, b1, b2, b3, B, M);

    // ---- GCN0 aggregation + bias bg0 + lrelu: B -> A ----
    gcn_agg_csr_kernel<1><<<agg_blocks, 256, 0, stream>>>(B, es, ces, rowptr, cnt, dis, bg0, A, M);

    // ---- GCN1 flipped: raw aggregation A -> B, then GEMM(+bg1+lrelu+Wo dot) -> ho ----
    gcn_agg_csr_kernel<0><<<agg_blocks, 256, 0, stream>>>(A, es, ces, rowptr, cnt, dis, nullptr, B, M);
    gemm_ho_kernel<<<ho_blocks, 512, 0, stream>>>(B, Wimg + 4 * 34816, bg1, Wo, ho, M);

    // ---- GCN2 scalar aggregation ----
    out_csr_kernel<<<(M + 255) / 256, 256, 0, stream>>>(ho, es, ces, rowptr, cnt, dis, bo, out, M);
}